// Round 10
// baseline (122.959 us; speedup 1.0000x reference)
//
#include <hip/hip_runtime.h>
#include <math.h>

#define ROWLEN 4096
#define BLK 256

typedef unsigned long long u64;

__device__ __forceinline__ u64 umax64(u64 a, u64 b) { return a > b ? a : b; }
__device__ __forceinline__ u64 umin64(u64 a, u64 b) { return a < b ? a : b; }

// top-3 of the union of two sorted-descending u64 triples (validated rounds 8-9)
__device__ __forceinline__ void merge3k(u64& a0, u64& a1, u64& a2,
                                        u64 b0, u64 b1, u64 b2) {
    u64 r0 = umax64(a0, b0);
    u64 m0 = umin64(a0, b0);
    u64 M1 = umax64(a1, b1);
    u64 r1 = umax64(m0, umin64(r0, M1));
    u64 r2 = umax64(umin64(M1, m0), umax64(a2, b2));
    a0 = r0; a1 = r1; a2 = r2;
}

// monotone key: (map(value) << 32) | (4095 - idx); u64 '>' == jax.lax.top_k order
__device__ __forceinline__ u64 make_key(float v, int idx) {
    unsigned u = __float_as_uint(v);
    unsigned s = ((unsigned)(((int)u) >> 31)) | 0x80000000u;
    return ((u64)(u ^ s) << 32) | (unsigned)(4095 - idx);
}

// fold (v,idx) into (value,index) triple with strict '>' — elements arrive in
// increasing index order per lane, so ties keep the lower index (exact).
__device__ __forceinline__ void fold_vi(float v, int idx,
                                        float& v0, float& v1, float& v2,
                                        int& j0, int& j1, int& j2) {
    bool c0 = v > v0, c1 = v > v1, c2 = v > v2;
    v2 = c2 ? (c1 ? v1 : v) : v2;  j2 = c2 ? (c1 ? j1 : idx) : j2;
    v1 = c1 ? (c0 ? v0 : v) : v1;  j1 = c1 ? (c0 ? j0 : idx) : j1;
    v0 = c0 ? v : v0;              j0 = c0 ? idx : j0;
}

// read-only: per-row top-3 via float fold + key butterfly, scatter 3 probs
__global__ __launch_bounds__(BLK, 4) void topk_scatter(const float* __restrict__ in,
                                                       float* __restrict__ out,
                                                       int rows) {
    const int lane = threadIdx.x & 63;
    const int row  = blockIdx.x * 4 + (threadIdx.x >> 6);
    if (row >= rows) return;

    const float4* rin = reinterpret_cast<const float4*>(in + (size_t)row * ROWLEN);

    float v0 = -INFINITY, v1 = -INFINITY, v2 = -INFINITY;
    int   j0 = 0, j1 = 0, j2 = 0;
    #pragma unroll
    for (int j = 0; j < 16; ++j) {
        float4 d = rin[lane + 64 * j];
        const int e = 4 * (lane + 64 * j);
        fold_vi(d.x, e + 0, v0, v1, v2, j0, j1, j2);
        fold_vi(d.y, e + 1, v0, v1, v2, j0, j1, j2);
        fold_vi(d.z, e + 2, v0, v1, v2, j0, j1, j2);
        fold_vi(d.w, e + 3, v0, v1, v2, j0, j1, j2);
    }

    // 3 keys per lane (amortized), then 64-lane butterfly on keys (exact ties)
    u64 t0 = make_key(v0, j0);
    u64 t1 = make_key(v1, j1);
    u64 t2 = make_key(v2, j2);
    #pragma unroll
    for (int off = 1; off < 64; off <<= 1) {
        u64 b0 = __shfl_xor(t0, off);
        u64 b1 = __shfl_xor(t1, off);
        u64 b2 = __shfl_xor(t2, off);
        merge3k(t0, t1, t2, b0, b1, b2);
    }

    if (lane == 0) {
        unsigned m0 = (unsigned)(t0 >> 32);
        unsigned m1 = (unsigned)(t1 >> 32);
        unsigned m2 = (unsigned)(t2 >> 32);
        unsigned u0 = ((int)m0 < 0) ? (m0 ^ 0x80000000u) : ~m0;
        unsigned u1 = ((int)m1 < 0) ? (m1 ^ 0x80000000u) : ~m1;
        unsigned u2 = ((int)m2 < 0) ? (m2 ^ 0x80000000u) : ~m2;
        float a0 = __uint_as_float(u0);
        float a1 = __uint_as_float(u1);
        float a2 = __uint_as_float(u2);
        int i0 = 4095 - (int)(unsigned)(t0 & 0xFFFFFFFFu);
        int i1 = 4095 - (int)(unsigned)(t1 & 0xFFFFFFFFu);
        int i2 = 4095 - (int)(unsigned)(t2 & 0xFFFFFFFFu);

        const float e1   = __expf(a1 - a0);
        const float e2   = __expf(a2 - a0);
        const float invZ = 1.0f / (1.0f + e1 + e2);

        float* r = out + (size_t)row * ROWLEN;
        r[i0] = invZ;
        r[i1] = e1 * invZ;
        r[i2] = e2 * invZ;
    }
}

extern "C" void kernel_launch(void* const* d_in, const int* in_sizes, int n_in,
                              void* d_out, int out_size, void* d_ws, size_t ws_size,
                              hipStream_t stream) {
    const float* in  = (const float*)d_in[0];
    float*       out = (float*)d_out;
    const int rows   = in_sizes[0] / ROWLEN;     // 8*2048 = 16384

    // pure write stream: zero the whole output at memset rate (~6.8 TB/s measured)
    hipMemsetAsync(out, 0, (size_t)out_size * sizeof(float), stream);

    // pure read stream + 3-element scatter per row (stream-ordered after memset)
    const int blocks = (rows + 3) / 4;           // 4 rows (waves) per block
    topk_scatter<<<blocks, BLK, 0, stream>>>(in, out, rows);
}

// Round 11
// 89.765 us; speedup vs baseline: 1.3698x; 1.3698x over previous
//
#include <hip/hip_runtime.h>
#include <math.h>

#define ROWLEN 4096
#define BLK 256

typedef float vfloat4 __attribute__((ext_vector_type(4)));
typedef unsigned long long u64;

__device__ __forceinline__ u64 umax64(u64 a, u64 b) { return a > b ? a : b; }
__device__ __forceinline__ u64 umin64(u64 a, u64 b) { return a < b ? a : b; }

// top-3 of the union of two sorted-descending u64 triples (validated r8-r10)
__device__ __forceinline__ void merge3k(u64& a0, u64& a1, u64& a2,
                                        u64 b0, u64 b1, u64 b2) {
    u64 r0 = umax64(a0, b0);
    u64 m0 = umin64(a0, b0);
    u64 M1 = umax64(a1, b1);
    u64 r1 = umax64(m0, umin64(r0, M1));
    u64 r2 = umax64(umin64(M1, m0), umax64(a2, b2));
    a0 = r0; a1 = r1; a2 = r2;
}

// monotone key: (map(value) << 32) | (4095 - idx); u64 '>' == jax.lax.top_k order
__device__ __forceinline__ u64 make_key(float v, int idx) {
    unsigned u = __float_as_uint(v);
    unsigned s = ((unsigned)(((int)u) >> 31)) | 0x80000000u;
    return ((u64)(u ^ s) << 32) | (unsigned)(4095 - idx);
}

// fold (v,idx) into (value,index) triple with strict '>' — per-lane elements
// arrive in increasing index order, so ties keep the lower index (exact).
__device__ __forceinline__ void fold_vi(float v, int idx,
                                        float& v0, float& v1, float& v2,
                                        int& j0, int& j1, int& j2) {
    bool c0 = v > v0, c1 = v > v1, c2 = v > v2;
    v2 = c2 ? (c1 ? v1 : v) : v2;  j2 = c2 ? (c1 ? j1 : idx) : j2;
    v1 = c1 ? (c0 ? v0 : v) : v1;  j1 = c1 ? (c0 ? j0 : idx) : j1;
    v0 = c0 ? v : v0;              j0 = c0 ? idx : j0;
}

__global__ __launch_bounds__(BLK, 4) void topk_softmax_fused(const float* __restrict__ in,
                                                             float* __restrict__ out,
                                                             int rows) {
    const int lane = threadIdx.x & 63;
    const int row  = blockIdx.x * 4 + (threadIdx.x >> 6);
    if (row >= rows) return;

    const float4* rin  = reinterpret_cast<const float4*>(in  + (size_t)row * ROWLEN);
    vfloat4*      rout = reinterpret_cast<vfloat4*>(     out + (size_t)row * ROWLEN);

    // ---- issue ALL 16 row loads first (64 data VGPRs, max bytes in flight) ----
    float4 d0  = rin[lane];          float4 d1  = rin[lane + 64];
    float4 d2  = rin[lane + 128];    float4 d3  = rin[lane + 192];
    float4 d4  = rin[lane + 256];    float4 d5  = rin[lane + 320];
    float4 d6  = rin[lane + 384];    float4 d7  = rin[lane + 448];
    float4 d8  = rin[lane + 512];    float4 d9  = rin[lane + 576];
    float4 d10 = rin[lane + 640];    float4 d11 = rin[lane + 704];
    float4 d12 = rin[lane + 768];    float4 d13 = rin[lane + 832];
    float4 d14 = rin[lane + 896];    float4 d15 = rin[lane + 960];
    __builtin_amdgcn_sched_barrier(0);   // loads stay above, folds below

    // ---- fold: waits here count ONLY loads (stores not yet issued) ----
    float v0 = -INFINITY, v1 = -INFINITY, v2 = -INFINITY;
    int   j0 = 0, j1 = 0, j2 = 0;
    #define FOLD4(D, J) do {                                   \
        const int e_ = 4 * (lane + 64 * (J));                  \
        fold_vi((D).x, e_ + 0, v0, v1, v2, j0, j1, j2);        \
        fold_vi((D).y, e_ + 1, v0, v1, v2, j0, j1, j2);        \
        fold_vi((D).z, e_ + 2, v0, v1, v2, j0, j1, j2);        \
        fold_vi((D).w, e_ + 3, v0, v1, v2, j0, j1, j2);        \
    } while (0)
    FOLD4(d0, 0);   FOLD4(d1, 1);   FOLD4(d2, 2);   FOLD4(d3, 3);
    FOLD4(d4, 4);   FOLD4(d5, 5);   FOLD4(d6, 6);   FOLD4(d7, 7);
    FOLD4(d8, 8);   FOLD4(d9, 9);   FOLD4(d10, 10); FOLD4(d11, 11);
    FOLD4(d12, 12); FOLD4(d13, 13); FOLD4(d14, 14); FOLD4(d15, 15);
    #undef FOLD4
    __builtin_amdgcn_sched_barrier(0);   // stores stay below the folds

    // ---- zero-fill row: 16 nt stores; latency hides under butterfly ----
    vfloat4 z; z.x = 0.0f; z.y = 0.0f; z.z = 0.0f; z.w = 0.0f;
    #pragma unroll
    for (int j = 0; j < 16; ++j)
        __builtin_nontemporal_store(z, &rout[lane + 64 * j]);

    // ---- 64-lane butterfly on u64 keys (exact jax.lax.top_k order) ----
    u64 t0 = make_key(v0, j0);
    u64 t1 = make_key(v1, j1);
    u64 t2 = make_key(v2, j2);
    #pragma unroll
    for (int off = 1; off < 64; off <<= 1) {
        u64 b0 = __shfl_xor(t0, off);
        u64 b1 = __shfl_xor(t1, off);
        u64 b2 = __shfl_xor(t2, off);
        merge3k(t0, t1, t2, b0, b1, b2);
    }

    // drain the wave's zero-fill stores before scattering into the same row
    asm volatile("s_waitcnt vmcnt(0)" ::: "memory");

    if (lane == 0) {
        unsigned m0 = (unsigned)(t0 >> 32);
        unsigned m1 = (unsigned)(t1 >> 32);
        unsigned m2 = (unsigned)(t2 >> 32);
        unsigned u0 = ((int)m0 < 0) ? (m0 ^ 0x80000000u) : ~m0;
        unsigned u1 = ((int)m1 < 0) ? (m1 ^ 0x80000000u) : ~m1;
        unsigned u2 = ((int)m2 < 0) ? (m2 ^ 0x80000000u) : ~m2;
        float a0 = __uint_as_float(u0);
        float a1 = __uint_as_float(u1);
        float a2 = __uint_as_float(u2);
        int i0 = 4095 - (int)(unsigned)(t0 & 0xFFFFFFFFu);
        int i1 = 4095 - (int)(unsigned)(t1 & 0xFFFFFFFFu);
        int i2 = 4095 - (int)(unsigned)(t2 & 0xFFFFFFFFu);

        const float e1   = __expf(a1 - a0);
        const float e2   = __expf(a2 - a0);
        const float invZ = 1.0f / (1.0f + e1 + e2);

        float* r = out + (size_t)row * ROWLEN;
        r[i0] = invZ;
        r[i1] = e1 * invZ;
        r[i2] = e2 * invZ;
    }
}

extern "C" void kernel_launch(void* const* d_in, const int* in_sizes, int n_in,
                              void* d_out, int out_size, void* d_ws, size_t ws_size,
                              hipStream_t stream) {
    const float* in  = (const float*)d_in[0];
    float*       out = (float*)d_out;
    const int rows   = in_sizes[0] / ROWLEN;     // 8*2048 = 16384
    const int blocks = (rows + 3) / 4;           // 4 rows (waves) per block
    topk_softmax_fused<<<blocks, BLK, 0, stream>>>(in, out, rows);
}